// Round 10
// baseline (268.948 us; speedup 1.0000x reference)
//
#include <hip/hip_runtime.h>
#include <math.h>

#define BB 32
#define DD 256
#define KK 2048
#define HW 1024
#define CHW (DD*HW)
#define NN (BB*HW)         // 32768 rows
#define BETA 0.25f
#define RROWS 32
#define BIAS 0.125f

typedef __attribute__((ext_vector_type(8))) short short8v;   // 8 bf16 (4 VGPR)
typedef __attribute__((ext_vector_type(4))) float f32x4;

__device__ __forceinline__ unsigned bfr(float f) {           // fp32 -> bf16 RNE
    unsigned u = __float_as_uint(f);
    return (u + 0x7FFFu + ((u >> 16) & 1u)) >> 16;
}
__device__ __forceinline__ unsigned bfpack(float lo, float hi) {
    return bfr(lo) | (bfr(hi) << 16);
}

// ---- prep: blocks 0..255 convert E->bf16 tiled; blocks 256..263 compute C ----
// EbfT unit u = t*2048 + c*256 + kc*64 + code64   (t = 64-code tile)
__global__ __launch_bounds__(256) void k_prep(const float* __restrict__ E,
                                              uint4* __restrict__ EbfT,
                                              float* __restrict__ Cref,
                                              float* __restrict__ Ckey) {
    int bid = blockIdx.x;
    if (bid < 256) {
        int u = bid * 256 + threadIdx.x;                 // 0..65535
        int code = u & 63, kc = (u >> 6) & 3, c = (u >> 8) & 7, t = u >> 11;
        int k = t * 64 + code;
        const float* s = E + ((size_t)k * DD + c * 32 + kc * 8);
        float4 f0 = *reinterpret_cast<const float4*>(s);
        float4 f1 = *reinterpret_cast<const float4*>(s + 4);
        uint4 o;
        o.x = bfpack(f0.x, f0.y); o.y = bfpack(f0.z, f0.w);
        o.z = bfpack(f1.x, f1.y); o.w = bfpack(f1.z, f1.w);
        EbfT[u] = o;
    } else {
        int k = (bid - 256) * 256 + threadIdx.x;
        const float* e = E + (size_t)k * DD;
        float res;
        {
#pragma clang fp contract(off)
            float r0[8], r1[8];
            #pragma unroll
            for (int j = 0; j < 8; ++j) { float t = e[j];       r0[j] = t * t; }
            #pragma unroll
            for (int j = 0; j < 8; ++j) { float t = e[128 + j]; r1[j] = t * t; }
            for (int i = 8; i < 128; i += 8) {
                #pragma unroll
                for (int j = 0; j < 8; ++j) { float t = e[i + j];       r0[j] += t * t; }
                #pragma unroll
                for (int j = 0; j < 8; ++j) { float t = e[128 + i + j]; r1[j] += t * t; }
            }
            float lo = ((r0[0]+r0[1])+(r0[2]+r0[3]))+((r0[4]+r0[5])+(r0[6]+r0[7]));
            float hi = ((r1[0]+r1[1])+(r1[2]+r1[3]))+((r1[4]+r1[5])+(r1[6]+r1[7]));
            res = lo + hi;
        }
        Cref[k] = res;
        Ckey[k] = res + BIAS;
    }
}

// ---- MFMA screen v6: K-split x2 for TLP. grid 1024 (4 blocks/CU, 16 waves/CU).
//      A in regs, B direct global->reg (E L2-resident). Each block: 64 rows x
//      16 tiles (half the codebook) -> top-4 per row-half. ----
__global__ __launch_bounds__(256, 4) void k_screen(
        const float* __restrict__ X, const uint4* __restrict__ EbfT,
        const float* __restrict__ Ckey, uint2* __restrict__ ck)
{
    __shared__ __align__(1024) char lds[32768];   // merge only (mb; scr aliases)

    const int tid = threadIdx.x;
    const int w = tid >> 6;              // 0..3
    const int wr = w >> 1, wc = w & 1;   // 2 row-groups x 2 code-groups
    const int lane = tid & 63;
    const int lid = lane & 15, kc = lane >> 4;
    const int bid = blockIdx.x;
    const int half = bid & 1;
    const int tbase = half * 16;
    const int nb = (bid >> 1) * 64;
    const int b = nb >> 10;              // 64 | 1024 -> single b per block
    const int hw0 = nb & 1023;

    // ---- A-fragments: rows hw0+wr*32+rt*16+lid, d = c*32+kc*8+j (64 VGPR) ----
    short8v a[8][2];
    {
        const float* xb = X + (size_t)b * CHW + (hw0 + wr * 32 + lid);
        #pragma unroll
        for (int c = 0; c < 8; ++c)
            #pragma unroll
            for (int rt = 0; rt < 2; ++rt) {
                const float* pp = xb + rt * 16 + (size_t)(c * 32 + kc * 8) * HW;
                float f[8];
                #pragma unroll
                for (int j = 0; j < 8; ++j) f[j] = pp[(size_t)j * HW];
                uint4 v;
                v.x = bfpack(f[0], f[1]); v.y = bfpack(f[2], f[3]);
                v.z = bfpack(f[4], f[5]); v.w = bfpack(f[6], f[7]);
                a[c][rt] = *reinterpret_cast<short8v*>(&v);
            }
    }

    unsigned t1[2][2][4], t2[2][2][4];                   // top-2 per (rt,ct,g)
    #pragma unroll
    for (int i = 0; i < 2; ++i)
        #pragma unroll
        for (int j = 0; j < 2; ++j)
            #pragma unroll
            for (int g = 0; g < 4; ++g) {
                t1[i][j][g] = 0xFFFFFFFFu; t2[i][j][g] = 0xFFFFFFFFu;
            }

    f32x4 acc[2][2];
    #pragma unroll
    for (int i = 0; i < 2; ++i)
        #pragma unroll
        for (int j = 0; j < 2; ++j) acc[i][j] = (f32x4){0.f, 0.f, 0.f, 0.f};

    const uint4* ebase = EbfT + (kc * 64 + wc * 32 + lid);
    const float* ckbase = Ckey + (wc * 32 + lid);
    float pckv0 = 0.f, pckv1 = 0.f;

    #pragma unroll 1
    for (int t = tbase; t < tbase + 16; ++t) {
        // 1) issue tile-t B loads (global->VGPR, L2-hot, coalesced 256B runs)
        uint4 braw[2][8];
        #pragma unroll
        for (int c = 0; c < 8; ++c) {
            braw[0][c] = ebase[t * 2048 + c * 256];
            braw[1][c] = ebase[t * 2048 + c * 256 + 16];
        }
        float nckv0 = ckbase[t * 64];
        float nckv1 = ckbase[t * 64 + 16];

        // 2) selection for tile t-1 (pure VALU — runs while loads in flight)
        if (t > tbase) {
            unsigned tt = (unsigned)(t - 1);
            #pragma unroll
            for (int rt = 0; rt < 2; ++rt)
                #pragma unroll
                for (int ct = 0; ct < 2; ++ct) {
                    float cv = ct ? pckv1 : pckv0;
                    #pragma unroll
                    for (int g = 0; g < 4; ++g) {
                        float s = fmaf(-2.0f, acc[rt][ct][g], cv);
                        unsigned key = (__float_as_uint(s) & 0xFFFFFFE0u) | tt;
                        unsigned o1 = t1[rt][ct][g];
                        unsigned hi = key > o1 ? key : o1;
                        t1[rt][ct][g] = key < o1 ? key : o1;
                        t2[rt][ct][g] = hi < t2[rt][ct][g] ? hi : t2[rt][ct][g];
                        acc[rt][ct][g] = 0.0f;
                    }
                }
        }
        pckv0 = nckv0; pckv1 = nckv1;

        // 3) MFMAs
        #pragma unroll
        for (int c = 0; c < 8; ++c) {
            short8v b0 = *reinterpret_cast<short8v*>(&braw[0][c]);
            short8v b1 = *reinterpret_cast<short8v*>(&braw[1][c]);
            acc[0][0] = __builtin_amdgcn_mfma_f32_16x16x32_bf16(a[c][0], b0, acc[0][0], 0, 0, 0);
            acc[1][0] = __builtin_amdgcn_mfma_f32_16x16x32_bf16(a[c][1], b0, acc[1][0], 0, 0, 0);
            acc[0][1] = __builtin_amdgcn_mfma_f32_16x16x32_bf16(a[c][0], b1, acc[0][1], 0, 0, 0);
            acc[1][1] = __builtin_amdgcn_mfma_f32_16x16x32_bf16(a[c][1], b1, acc[1][1], 0, 0, 0);
        }
    }
    // final selection (tile tbase+15)
    {
        unsigned tt = (unsigned)(tbase + 15);
        #pragma unroll
        for (int rt = 0; rt < 2; ++rt)
            #pragma unroll
            for (int ct = 0; ct < 2; ++ct) {
                float cv = ct ? pckv1 : pckv0;
                #pragma unroll
                for (int g = 0; g < 4; ++g) {
                    float s = fmaf(-2.0f, acc[rt][ct][g], cv);
                    unsigned key = (__float_as_uint(s) & 0xFFFFFFE0u) | tt;
                    unsigned o1 = t1[rt][ct][g];
                    unsigned hi = key > o1 ? key : o1;
                    t1[rt][ct][g] = key < o1 ? key : o1;
                    t2[rt][ct][g] = hi < t2[rt][ct][g] ? hi : t2[rt][ct][g];
                }
            }
    }

    // ---- merge: 64 slots/row x 2 keys -> top-4 of this half ----
    uint2* mb = reinterpret_cast<uint2*>(lds);            // [64 rows][64 slots] 32KB
    #pragma unroll
    for (int rt = 0; rt < 2; ++rt)
        #pragma unroll
        for (int ct = 0; ct < 2; ++ct)
            #pragma unroll
            for (int g = 0; g < 4; ++g) {
                int row = wr * 32 + rt * 16 + kc * 4 + g;
                int slot = wc * 32 + ct * 16 + lid;
                uint2 v; v.x = t1[rt][ct][g]; v.y = t2[rt][ct][g];
                mb[row * 64 + slot] = v;
            }
    __syncthreads();
    int row = tid >> 2, q = tid & 3;
    uint2 kv[16]; int sl[16];
    #pragma unroll
    for (int s = 0; s < 16; ++s) {
        int slot = q * 16 + ((s + tid) & 15);             // bank-spread rotation
        kv[s] = mb[row * 64 + slot];
        sl[s] = slot;
    }
    __syncthreads();                                      // all of mb in regs now
    uint2* scr = reinterpret_cast<uint2*>(lds);           // alias: [64][4][4] 8KB
    {
        unsigned prev = 0; int prevj = -1;
        for (int i = 0; i < 4; ++i) {
            unsigned cur = 0xFFFFFFFFu; int curj = 0x7FFFFFFF;
            #pragma unroll
            for (int s = 0; s < 16; ++s) {
                int j0 = sl[s] * 2;
                { unsigned k2=kv[s].x; int j=j0;   if ((k2>prev||(k2==prev&&j>prevj)) && (k2<cur||(k2==cur&&j<curj))) {cur=k2;curj=j;} }
                { unsigned k2=kv[s].y; int j=j0+1; if ((k2>prev||(k2==prev&&j>prevj)) && (k2<cur||(k2==cur&&j<curj))) {cur=k2;curj=j;} }
            }
            uint2 pr; pr.x = cur; pr.y = (unsigned)curj;
            scr[(row * 4 + q) * 4 + i] = pr;
            prev = cur; prevj = curj;
        }
    }
    __syncthreads();
    if (tid < 64) {
        unsigned prev = 0; int prevj = -1;
        unsigned short codes[4];
        for (int i = 0; i < 4; ++i) {
            unsigned cur = 0xFFFFFFFFu; int curj = 0x7FFFFFFF;
            for (int m = 0; m < 16; ++m) {
                int mm = (m + tid) & 15;
                uint2 pr = scr[tid * 16 + mm];
                unsigned k2 = pr.x; int j = (int)pr.y;
                if ((k2>prev||(k2==prev&&j>prevj)) && (k2<cur||(k2==cur&&j<curj))) {cur=k2;curj=j;}
            }
            prev = cur; prevj = curj;
            codes[i] = (unsigned short)((cur & 31u) * 64 + (curj >> 1));  // t*64+slot
        }
        uint2 o;
        o.x = (unsigned)codes[0] | ((unsigned)codes[1] << 16);
        o.y = (unsigned)codes[2] | ((unsigned)codes[3] << 16);
        ck[(size_t)(nb + tid) * 2 + half] = o;
    }
}

// ---- refine+out: np-fp32 rescore of 8 cands with coalesced LDS E-staging,
//      then fused output write. 32 rows/block, 8 lanes per (row,cand-chunk). ----
__global__ __launch_bounds__(256) void k_refineout(const float* __restrict__ X,
                                                   const float* __restrict__ E,
                                                   const float* __restrict__ Cref,
                                                   const uint2* __restrict__ ck,
                                                   float* __restrict__ idx_out_f,
                                                   float* __restrict__ out) {
    __shared__ float Xl[RROWS][DD + 4];
    __shared__ float El[RROWS][DD + 4];
    __shared__ int kl[RROWS][8];
    __shared__ int bk_l[RROWS];
    const int tid = threadIdx.x;
    const int n0 = blockIdx.x * RROWS;
    const int b = n0 >> 10;
    const int hw0 = n0 & 1023;
    const float* xbase = X + (size_t)b * CHW + hw0;
    #pragma unroll
    for (int it = 0; it < RROWS; ++it) {
        int idx = tid + it * 256;
        int d = idx >> 5, r = idx & 31;
        Xl[r][d] = xbase[(size_t)d * HW + r];
    }
    const int r = tid >> 3, c = tid & 7;                  // 8 lanes per row
    {   // candidate table: c 0..3 from half0, 4..7 from half1
        uint2 h = ck[(size_t)(n0 + r) * 2 + (c >> 2)];
        int ii = c & 3;
        unsigned wsel = (ii >> 1) ? h.y : h.x;
        kl[r][c] = (ii & 1) ? (int)(wsel >> 16) : (int)(wsel & 0xFFFFu);
    }
    __syncthreads();
    float A;
    {
#pragma clang fp contract(off)
        float r0[8], r1[8];
        #pragma unroll
        for (int j = 0; j < 8; ++j) { float t = Xl[r][j];       r0[j] = t * t; }
        #pragma unroll
        for (int j = 0; j < 8; ++j) { float t = Xl[r][128 + j]; r1[j] = t * t; }
        for (int i = 8; i < 128; i += 8) {
            #pragma unroll
            for (int j = 0; j < 8; ++j) { float t = Xl[r][i + j];       r0[j] += t * t; }
            #pragma unroll
            for (int j = 0; j < 8; ++j) { float t = Xl[r][128 + i + j]; r1[j] += t * t; }
        }
        float lo = ((r0[0]+r0[1])+(r0[2]+r0[3]))+((r0[4]+r0[5])+(r0[6]+r0[7]));
        float hi = ((r1[0]+r1[1])+(r1[2]+r1[3]))+((r1[4]+r1[5])+(r1[6]+r1[7]));
        A = lo + hi;
    }
    float bd = INFINITY; int bk = 0x7FFFFFFF;
    for (int cc = 0; cc < 8; ++cc) {
        __syncthreads();                       // prev chunk's El reads complete
        {   // stage 32 E-rows coalesced: 8 stagers/row, 128B runs
            int kk = kl[r][cc];
            const float* er = E + (size_t)kk * DD;
            #pragma unroll
            for (int m = 0; m < 8; ++m)
                *reinterpret_cast<float4*>(&El[r][m * 32 + c * 4]) =
                    *reinterpret_cast<const float4*>(er + m * 32 + c * 4);
        }
        __syncthreads();
        double p = 0.0;                        // f64 partial: order-free proxy
        #pragma unroll
        for (int m = 0; m < 8; ++m) {
            float4 xv = *reinterpret_cast<const float4*>(&Xl[r][c * 32 + m * 4]);
            float4 ev = *reinterpret_cast<const float4*>(&El[r][c * 32 + m * 4]);
            p += (double)xv.x*ev.x + (double)xv.y*ev.y
               + (double)xv.z*ev.z + (double)xv.w*ev.w;
        }
        p += __shfl_xor(p, 1, 64);
        p += __shfl_xor(p, 2, 64);
        p += __shfl_xor(p, 4, 64);
        if (c == 0) {
            int kk = kl[r][cc];
            float dist;
            {
#pragma clang fp contract(off)
                float M  = (float)p;
                float Bt = 2.0f * M;
                float T1 = A - Bt;
                dist = T1 + Cref[kk];
            }
            if (dist < bd || (dist == bd && kk < bk)) { bd = dist; bk = kk; }
        }
    }
    if (c == 0) {
        bk_l[r] = bk;
        idx_out_f[n0 + r] = (float)bk;
    }
    __syncthreads();
    {   // stage winning E rows (coalesced), then fused output write
        int kk = bk_l[r];
        const float* er = E + (size_t)kk * DD;
        #pragma unroll
        for (int m = 0; m < 8; ++m)
            *reinterpret_cast<float4*>(&El[r][m * 32 + c * 4]) =
                *reinterpret_cast<const float4*>(er + m * 32 + c * 4);
    }
    __syncthreads();
    {
        const int rr = tid & 31;
        const int d0 = tid >> 5;               // 0..7
        float* ob = out + (size_t)b * CHW + hw0 + rr;
        #pragma unroll
        for (int it = 0; it < 32; ++it) {
            int d = d0 + it * 8;
            float x = Xl[rr][d];
            float qv = El[rr][d];
            ob[(size_t)d * HW] = x + BETA * (qv - x);
        }
    }
}

extern "C" void kernel_launch(void* const* d_in, const int* in_sizes, int n_in,
                              void* d_out, int out_size, void* d_ws, size_t ws_size,
                              hipStream_t stream) {
    const float* lat = (const float*)d_in[0];      // (32,256,32,32) fp32
    const float* emb = (const float*)d_in[1];      // (2048,256) fp32
    float* out   = (float*)d_out;                  // 8388608 floats (output 0)
    float* idx_f = out + (size_t)BB * DD * HW;     // 32768 floats (output 1)

    // EbfT scratch in d_out (read only by k_screen, which completes before
    // k_refineout writes out). Ckey/Cref/ck in d_ws (~530 KB).
    char*  ob   = (char*)d_out;
    uint4* EbfT = (uint4*)(ob);                    // 1 MB

    char* ws = (char*)d_ws;
    float* Ckey = (float*)(ws + 0);                // 8 KB
    float* Cref = (float*)(ws + 8192);             // 8 KB
    uint2* ck   = (uint2*)(ws + 16384);            // 512 KB (2 x ushort4 per row)

    k_prep      <<<264, 256, 0, stream>>>(emb, EbfT, Cref, Ckey);
    k_screen    <<<NN / 64 * 2, 256, 0, stream>>>(lat, EbfT, Ckey, ck);
    k_refineout <<<NN / RROWS, 256, 0, stream>>>(lat, emb, Cref, ck, idx_f, out);
}

// Round 11
// 156.218 us; speedup vs baseline: 1.7216x; 1.7216x over previous
//
#include <hip/hip_runtime.h>
#include <math.h>

#define BB 32
#define DD 256
#define KK 2048
#define HW 1024
#define CHW (DD*HW)
#define NN (BB*HW)         // 32768 rows
#define BETA 0.25f
#define RROWS 16
#define BIAS 0.125f

typedef __attribute__((ext_vector_type(8))) short short8v;   // 8 bf16 (4 VGPR)
typedef __attribute__((ext_vector_type(4))) float f32x4;

typedef const __attribute__((address_space(1))) void gv_t;
typedef __attribute__((address_space(3))) void lv_t;

__device__ __forceinline__ void gl_lds16(const void* g, void* l) {
    // LDS dest = wave-uniform base (+ lane*16 by HW); global src = per-lane addr
    __builtin_amdgcn_global_load_lds((gv_t*)g, (lv_t*)l, 16, 0, 0);
}

__device__ __forceinline__ unsigned bfr(float f) {           // fp32 -> bf16 RNE
    unsigned u = __float_as_uint(f);
    return (u + 0x7FFFu + ((u >> 16) & 1u)) >> 16;
}
__device__ __forceinline__ unsigned bfpack(float lo, float hi) {
    return bfr(lo) | (bfr(hi) << 16);
}

#define BARRIER() do { asm volatile("" ::: "memory"); \
                       __builtin_amdgcn_s_barrier();  \
                       asm volatile("" ::: "memory"); } while (0)

// ---- prep: blocks 0..255 convert E->bf16 tiled; blocks 256..263 compute C ----
// EbfT unit u = t*2048 + c*256 + kc*64 + code64   (t = 64-code tile)
__global__ __launch_bounds__(256) void k_prep(const float* __restrict__ E,
                                              uint4* __restrict__ EbfT,
                                              float* __restrict__ Cref,
                                              float* __restrict__ Ckey) {
    int bid = blockIdx.x;
    if (bid < 256) {
        int u = bid * 256 + threadIdx.x;                 // 0..65535
        int code = u & 63, kc = (u >> 6) & 3, c = (u >> 8) & 7, t = u >> 11;
        int k = t * 64 + code;
        const float* s = E + ((size_t)k * DD + c * 32 + kc * 8);
        float4 f0 = *reinterpret_cast<const float4*>(s);
        float4 f1 = *reinterpret_cast<const float4*>(s + 4);
        uint4 o;
        o.x = bfpack(f0.x, f0.y); o.y = bfpack(f0.z, f0.w);
        o.z = bfpack(f1.x, f1.y); o.w = bfpack(f1.z, f1.w);
        EbfT[u] = o;
    } else {
        int k = (bid - 256) * 256 + threadIdx.x;
        const float* e = E + (size_t)k * DD;
        float res;
        {
#pragma clang fp contract(off)
            float r0[8], r1[8];
            #pragma unroll
            for (int j = 0; j < 8; ++j) { float t = e[j];       r0[j] = t * t; }
            #pragma unroll
            for (int j = 0; j < 8; ++j) { float t = e[128 + j]; r1[j] = t * t; }
            for (int i = 8; i < 128; i += 8) {
                #pragma unroll
                for (int j = 0; j < 8; ++j) { float t = e[i + j];       r0[j] += t * t; }
                #pragma unroll
                for (int j = 0; j < 8; ++j) { float t = e[128 + i + j]; r1[j] += t * t; }
            }
            float lo = ((r0[0]+r0[1])+(r0[2]+r0[3]))+((r0[4]+r0[5])+(r0[6]+r0[7]));
            float hi = ((r1[0]+r1[1])+(r1[2]+r1[3]))+((r1[4]+r1[5])+(r1[6]+r1[7]));
            res = lo + hi;
        }
        Cref[k] = res;
        Ckey[k] = res + BIAS;
    }
}

// ---- MFMA screen v8: 512 thr = 8 waves (4 row-grp x 16 rows, 2 code-grp),
//      64 rows/block, K-split x2 (16 tiles/block), grid 1024 (2 blocks/CU,
//      4 waves/SIMD). A=32 VGPR in regs; E LDS dbuf + counted vmcnt (r8 scheme).
__global__ __launch_bounds__(512, 4) void k_screen(
        const float* __restrict__ X, const uint4* __restrict__ EbfT,
        const float* __restrict__ Ckey, uint2* __restrict__ ck)
{
    __shared__ __align__(1024) char lds[69632];   // 2x32KB E dbuf | 4KB ckl

    const int tid = threadIdx.x;
    const int w = tid >> 6;              // 0..7
    const int rg = w >> 1;               // 0..3 row group (16 rows each)
    const int cg = w & 1;                // 0..1 code group (32 codes each)
    const int lane = tid & 63;
    const int lid = lane & 15, kc = lane >> 4;
    const int bid = blockIdx.x;
    const int half = bid & 1;
    const int tbase = half * 16;
    const int nb = (bid >> 1) * 64;
    const int b = nb >> 10;              // 64 | 1024 -> single b per block
    const int hw0 = nb & 1023;

    float* ckl = (float*)(lds + 65536);

    // prologue: Ckey chunk -> regs (then LDS), A -> regs, stage tiles 0,1
    float ckg0 = Ckey[tbase * 64 + tid];
    float ckg1 = Ckey[tbase * 64 + 512 + tid];

    short8v a[8];                        // 16 rows x 256 d: 32 VGPR
    {
        const float* xb = X + (size_t)b * CHW + (hw0 + rg * 16 + lid);
        #pragma unroll
        for (int c = 0; c < 8; ++c) {
            const float* pp = xb + (size_t)(c * 32 + kc * 8) * HW;
            float f[8];
            #pragma unroll
            for (int j = 0; j < 8; ++j) f[j] = pp[(size_t)j * HW];
            uint4 v;
            v.x = bfpack(f[0], f[1]); v.y = bfpack(f[2], f[3]);
            v.z = bfpack(f[4], f[5]); v.w = bfpack(f[6], f[7]);
            a[c] = *reinterpret_cast<short8v*>(&v);
        }
    }
    ckl[tid] = ckg0;
    ckl[tid + 512] = ckg1;

    auto stage = [&](int t, int p) {     // t local (0..15); 8 waves x 4 x 1KB
        const uint4* src = EbfT + ((size_t)(tbase + t) * 2048 + w * 256 + lane);
        char* dst = lds + p * 32768 + (w * 256) * 16;
        #pragma unroll
        for (int i = 0; i < 4; ++i)
            gl_lds16(src + i * 64, dst + i * 1024);
    };
    stage(0, 0);
    stage(1, 1);
    asm volatile("s_waitcnt vmcnt(0) lgkmcnt(0)" ::: "memory");
    BARRIER();

    unsigned t1[2][4], t2[2][4];         // top-2 per (ct,g)
    #pragma unroll
    for (int j = 0; j < 2; ++j)
        #pragma unroll
        for (int g = 0; g < 4; ++g) { t1[j][g] = 0xFFFFFFFFu; t2[j][g] = 0xFFFFFFFFu; }

    f32x4 acc[2];
    acc[0] = (f32x4){0.f, 0.f, 0.f, 0.f};
    acc[1] = (f32x4){0.f, 0.f, 0.f, 0.f};

    int p = 0;
    float pck0 = 0.f, pck1 = 0.f;
    #pragma unroll 1
    for (int tt = 0; tt < 16; ++tt) {
        float ck0 = ckl[tt * 64 + cg * 32 + lid];
        float ck1 = ckl[tt * 64 + cg * 32 + 16 + lid];

        // selection for tile tt-1 (register-only, overlaps ds_read latency)
        if (tt > 0) {
            unsigned tg = (unsigned)(tbase + tt - 1);
            #pragma unroll
            for (int ct = 0; ct < 2; ++ct) {
                float cv = ct ? pck1 : pck0;
                #pragma unroll
                for (int g = 0; g < 4; ++g) {
                    float s = fmaf(-2.0f, acc[ct][g], cv);
                    unsigned key = (__float_as_uint(s) & 0xFFFFFFE0u) | tg;
                    unsigned o1 = t1[ct][g];
                    unsigned hi = key > o1 ? key : o1;
                    t1[ct][g] = key < o1 ? key : o1;
                    t2[ct][g] = hi < t2[ct][g] ? hi : t2[ct][g];
                    acc[ct][g] = 0.0f;
                }
            }
        }
        pck0 = ck0; pck1 = ck1;

        const short8v* Ev = reinterpret_cast<const short8v*>(lds + p * 32768);
        #pragma unroll
        for (int c = 0; c < 8; ++c) {
            short8v b0 = Ev[c * 256 + kc * 64 + cg * 32 + lid];
            short8v b1 = Ev[c * 256 + kc * 64 + cg * 32 + 16 + lid];
            acc[0] = __builtin_amdgcn_mfma_f32_16x16x32_bf16(a[c], b0, acc[0], 0, 0, 0);
            acc[1] = __builtin_amdgcn_mfma_f32_16x16x32_bf16(a[c], b1, acc[1], 0, 0, 0);
        }

        BARRIER();                                   // all waves done with buf p
        if (tt < 14) {
            stage(tt + 2, p);                        // refill buf p (2-deep)
            asm volatile("s_waitcnt vmcnt(4)" ::: "memory");  // tile tt+1 ready
        } else {
            asm volatile("s_waitcnt vmcnt(0)" ::: "memory");
        }
        BARRIER();
        p ^= 1;
    }
    // final selection (tile tbase+15)
    {
        unsigned tg = (unsigned)(tbase + 15);
        #pragma unroll
        for (int ct = 0; ct < 2; ++ct) {
            float cv = ct ? pck1 : pck0;
            #pragma unroll
            for (int g = 0; g < 4; ++g) {
                float s = fmaf(-2.0f, acc[ct][g], cv);
                unsigned key = (__float_as_uint(s) & 0xFFFFFFE0u) | tg;
                unsigned o1 = t1[ct][g];
                unsigned hi = key > o1 ? key : o1;
                t1[ct][g] = key < o1 ? key : o1;
                t2[ct][g] = hi < t2[ct][g] ? hi : t2[ct][g];
            }
        }
    }

    // ---- merge: 64 slots/row x 2 keys -> top-4 of this half ----
    uint2* mb = reinterpret_cast<uint2*>(lds);            // [64 rows][64 slots] 32KB
    uint2* scr = reinterpret_cast<uint2*>(lds + 32768);   // [64][4][4] 8KB
    #pragma unroll
    for (int ct = 0; ct < 2; ++ct)
        #pragma unroll
        for (int g = 0; g < 4; ++g) {
            int row = rg * 16 + kc * 4 + g;
            int slot = cg * 32 + ct * 16 + lid;
            uint2 v; v.x = t1[ct][g]; v.y = t2[ct][g];
            mb[row * 64 + slot] = v;
        }
    BARRIER();
    if (tid < 256) {
        int row = tid >> 2, q = tid & 3;
        unsigned prev = 0; int prevj = -1;
        for (int i = 0; i < 4; ++i) {
            unsigned cur = 0xFFFFFFFFu; int curj = 0x7FFFFFFF;
            #pragma unroll
            for (int s = 0; s < 16; ++s) {
                int slot = q * 16 + ((s + tid) & 15);     // bank-spread rotation
                uint2 kv = mb[row * 64 + slot];
                int j0 = slot * 2;
                { unsigned k2=kv.x; int j=j0;   if ((k2>prev||(k2==prev&&j>prevj)) && (k2<cur||(k2==cur&&j<curj))) {cur=k2;curj=j;} }
                { unsigned k2=kv.y; int j=j0+1; if ((k2>prev||(k2==prev&&j>prevj)) && (k2<cur||(k2==cur&&j<curj))) {cur=k2;curj=j;} }
            }
            uint2 pr; pr.x = cur; pr.y = (unsigned)curj;
            scr[(row * 4 + q) * 4 + i] = pr;
            prev = cur; prevj = curj;
        }
    }
    BARRIER();
    if (tid < 64) {
        unsigned prev = 0; int prevj = -1;
        unsigned short codes[4];
        for (int i = 0; i < 4; ++i) {
            unsigned cur = 0xFFFFFFFFu; int curj = 0x7FFFFFFF;
            for (int m = 0; m < 16; ++m) {
                int mm = (m + tid) & 15;
                uint2 pr = scr[tid * 16 + mm];
                unsigned k2 = pr.x; int j = (int)pr.y;
                if ((k2>prev||(k2==prev&&j>prevj)) && (k2<cur||(k2==cur&&j<curj))) {cur=k2;curj=j;}
            }
            prev = cur; prevj = curj;
            codes[i] = (unsigned short)((cur & 31u) * 64 + (curj >> 1));  // t*64+slot
        }
        uint2 o;
        o.x = (unsigned)codes[0] | ((unsigned)codes[1] << 16);
        o.y = (unsigned)codes[2] | ((unsigned)codes[3] << 16);
        ck[(size_t)(nb + tid) * 2 + half] = o;
    }
}

// ---- refine+out v3: barrier-light. 16 rows/block, 16 lanes/row, direct-L2
//      E reads (no per-cand staging), f64 butterfly dot, fused output. ----
__global__ __launch_bounds__(256) void k_refineout(const float* __restrict__ X,
                                                   const float* __restrict__ E,
                                                   const float* __restrict__ Cref,
                                                   const uint2* __restrict__ ck,
                                                   float* __restrict__ idx_out_f,
                                                   float* __restrict__ out) {
    __shared__ float Xl[RROWS][DD + 4];
    __shared__ float El[RROWS][DD + 4];
    __shared__ int bk_l[RROWS];
    const int tid = threadIdx.x;
    const int n0 = blockIdx.x * RROWS;
    const int b = n0 >> 10;
    const int hw0 = n0 & 1023;
    const float* xbase = X + (size_t)b * CHW + hw0;
    #pragma unroll
    for (int it = 0; it < RROWS; ++it) {
        int idx = tid + it * 256;
        int d = idx >> 4, rr = idx & 15;
        Xl[rr][d] = xbase[(size_t)d * HW + rr];
    }
    __syncthreads();
    const int r = tid >> 4, c = tid & 15;
    const int sub = c & 7;
    uint4 ck4 = reinterpret_cast<const uint4*>(ck)[n0 + r];   // 8 ushort codes
    const unsigned short* cs = reinterpret_cast<const unsigned short*>(&ck4);
    float A;
    {
#pragma clang fp contract(off)
        float r0[8], r1[8];
        #pragma unroll
        for (int j = 0; j < 8; ++j) { float t = Xl[r][j];       r0[j] = t * t; }
        #pragma unroll
        for (int j = 0; j < 8; ++j) { float t = Xl[r][128 + j]; r1[j] = t * t; }
        for (int i = 8; i < 128; i += 8) {
            #pragma unroll
            for (int j = 0; j < 8; ++j) { float t = Xl[r][i + j];       r0[j] += t * t; }
            #pragma unroll
            for (int j = 0; j < 8; ++j) { float t = Xl[r][128 + i + j]; r1[j] += t * t; }
        }
        float lo = ((r0[0]+r0[1])+(r0[2]+r0[3]))+((r0[4]+r0[5])+(r0[6]+r0[7]));
        float hi = ((r1[0]+r1[1])+(r1[2]+r1[3]))+((r1[4]+r1[5])+(r1[6]+r1[7]));
        A = lo + hi;
    }
    float bd = INFINITY; int bk = 0x7FFFFFFF;
    #pragma unroll 1
    for (int cc = 0; cc < 4; ++cc) {
        int k = cs[cc * 2 + (c >> 3)];
        const float* er = E + (size_t)k * DD;
        double p = 0.0;                          // f64: order-free proxy
        #pragma unroll
        for (int m = 0; m < 8; ++m) {
            float4 ev = *reinterpret_cast<const float4*>(er + sub * 32 + m * 4);
            float4 xv = *reinterpret_cast<const float4*>(&Xl[r][sub * 32 + m * 4]);
            p += (double)xv.x*ev.x + (double)xv.y*ev.y
               + (double)xv.z*ev.z + (double)xv.w*ev.w;
        }
        p += __shfl_xor(p, 1, 64);
        p += __shfl_xor(p, 2, 64);
        p += __shfl_xor(p, 4, 64);
        float dist;
        {
#pragma clang fp contract(off)
            float M  = (float)p;
            float Bt = 2.0f * M;
            float T1 = A - Bt;
            dist = T1 + Cref[k];
        }
        if (dist < bd || (dist == bd && k < bk)) { bd = dist; bk = k; }
    }
    // combine the two 8-lane candidate groups
    {
        float bd2 = __shfl_xor(bd, 8, 64);
        int   bk2 = __shfl_xor(bk, 8, 64);
        if (bd2 < bd || (bd2 == bd && bk2 < bk)) { bd = bd2; bk = bk2; }
    }
    if (c == 0) {
        bk_l[r] = bk;
        idx_out_f[n0 + r] = (float)bk;
    }
    __syncthreads();
    {   // stage winning E rows coalesced (256B runs), then fused output write
        int kk = bk_l[r];
        const float* er = E + (size_t)kk * DD;
        #pragma unroll
        for (int m = 0; m < 4; ++m)
            *reinterpret_cast<float4*>(&El[r][m * 64 + c * 4]) =
                *reinterpret_cast<const float4*>(er + m * 64 + c * 4);
    }
    __syncthreads();
    {
        const int rr = tid & 15;
        const int d0 = tid >> 4;                 // 0..15
        float* ob = out + (size_t)b * CHW + hw0 + rr;
        #pragma unroll
        for (int it = 0; it < 16; ++it) {
            int d = d0 + it * 16;
            float x = Xl[rr][d];
            float qv = El[rr][d];
            ob[(size_t)d * HW] = x + BETA * (qv - x);
        }
    }
}

extern "C" void kernel_launch(void* const* d_in, const int* in_sizes, int n_in,
                              void* d_out, int out_size, void* d_ws, size_t ws_size,
                              hipStream_t stream) {
    const float* lat = (const float*)d_in[0];      // (32,256,32,32) fp32
    const float* emb = (const float*)d_in[1];      // (2048,256) fp32
    float* out   = (float*)d_out;                  // 8388608 floats (output 0)
    float* idx_f = out + (size_t)BB * DD * HW;     // 32768 floats (output 1)

    // EbfT scratch in d_out (read only by k_screen, which completes before
    // k_refineout writes out). Ckey/Cref/ck in d_ws (~530 KB).
    char*  ob   = (char*)d_out;
    uint4* EbfT = (uint4*)(ob);                    // 1 MB

    char* ws = (char*)d_ws;
    float* Ckey = (float*)(ws + 0);                // 8 KB
    float* Cref = (float*)(ws + 8192);             // 8 KB
    uint2* ck   = (uint2*)(ws + 16384);            // 512 KB (2 x ushort4 per row)

    k_prep      <<<264, 256, 0, stream>>>(emb, EbfT, Cref, Ckey);
    k_screen    <<<NN / 64 * 2, 512, 0, stream>>>(lat, EbfT, Ckey, ck);
    k_refineout <<<NN / RROWS, 256, 0, stream>>>(lat, emb, Cref, ck, idx_f, out);
}